// Round 2
// baseline (1685.069 us; speedup 1.0000x reference)
//
#include <hip/hip_runtime.h>
#include <hip/hip_bf16.h>

// NEmbNet: per-expert 3-layer MLP + restricted softmax + scatter into identity.
// B=8192, F=512, H=1024, P=64, L=32, A=16.
// R2: ws-bounded design. Weights stay f32 in global; each GEMM reg-stages its
// B tile with fused f32->bf16 convert (float4 load -> cvt -> ds_write_b128).
// Activations (A operand) convert once to bf16 and use global_load_lds w16.
// Batch is chunked so ws usage = MC*5120 bytes always fits ws_size.

typedef short v8s __attribute__((ext_vector_type(8)));
typedef float v4f __attribute__((ext_vector_type(4)));

using bf16 = __hip_bfloat16;

#define AS_GLOBAL __attribute__((address_space(1)))
#define AS_LDS    __attribute__((address_space(3)))

static constexpr int Mtot = 8192;
static constexpr int Fdim = 512;
static constexpr int Hdim = 1024;
static constexpr int Pdim = 64;
static constexpr int Aexp = 16;

__device__ __forceinline__ void gload_lds16(const void* g, void* l) {
  __builtin_amdgcn_global_load_lds((const AS_GLOBAL void*)g, (AS_LDS void*)l, 16, 0, 0);
}
__device__ __forceinline__ short bfs(float x) {
  bf16 h = __float2bfloat16(x);
  return *(short*)&h;
}

// ---------------------------------------------------------------- converts
__global__ void f32_to_bf16_kernel(const float* __restrict__ in,
                                   unsigned short* __restrict__ outp, int n4) {
  int i = blockIdx.x * blockDim.x + threadIdx.x;
  int stride = gridDim.x * blockDim.x;
  for (; i < n4; i += stride) {
    float4 v = ((const float4*)in)[i];
    ushort4 u;
    u.x = (unsigned short)bfs(v.x);
    u.y = (unsigned short)bfs(v.y);
    u.z = (unsigned short)bfs(v.z);
    u.w = (unsigned short)bfs(v.w);
    ((ushort4*)outp)[i] = u;
  }
}

// ---------------------------------------------------------------- identity fill
__global__ void ident_kernel(float* __restrict__ outp) {
  const long total4 = (long)Mtot * Pdim * Pdim / 4;
  long i = blockIdx.x * 256 + threadIdx.x;
  const long stride = (long)gridDim.x * 256;
  for (; i < total4; i += stride) {
    long e = i * 4;
    int q = (int)(e & 63);
    int p = (int)((e >> 6) & 63);
    float4 v;
    v.x = (p == q)     ? 1.f : 0.f;
    v.y = (p == q + 1) ? 1.f : 0.f;
    v.z = (p == q + 2) ? 1.f : 0.f;
    v.w = (p == q + 3) ? 1.f : 0.f;
    *(float4*)&outp[e] = v;
  }
}

// ---------------------------------------------------------------- GEMM (NT) + bias + relu -> bf16
// C[M,N] = relu(A[M,K]bf16 @ Bw[N,K]f32^T + bias[N]); 128x128 tile, BK=64, 4 waves.
// B tile converted f32->bf16 in-register during staging.
__global__ __launch_bounds__(256) void gemm_bias_relu_kernel(
    const bf16* __restrict__ Ain, const float* __restrict__ Bw,
    const float* __restrict__ bias, bf16* __restrict__ Cout, int K, int N) {
  __shared__ short lsA[128 * 64];
  __shared__ short lsB[128 * 64];
  const int t = threadIdx.x;
  const int mBase = blockIdx.x * 128;
  const int nBase = blockIdx.y * 128;
  const int w = t >> 6, lane = t & 63;
  const int wm = w >> 1, wn = w & 1;
  const int lr = lane & 15, lk = lane >> 4;

  v4f acc[4][4];
#pragma unroll
  for (int m = 0; m < 4; ++m)
#pragma unroll
    for (int n = 0; n < 4; ++n) acc[m][n] = (v4f)(0.f);

  const int rowA = t >> 3;
  const int col8 = (t & 7) * 8;
  const bf16* gA = Ain + (size_t)(mBase + rowA) * K + col8;
  const int rB = t >> 1;             // 0..127
  const int cB = (t & 1) * 32;       // 0 or 32
  const float* gB = Bw + (size_t)(nBase + rB) * K + cB;

  for (int k0 = 0; k0 < K; k0 += 64) {
    // B: 8x float4 f32 load -> cvt -> 4x ds_write_b128 (bf16)
    const float4* src = (const float4*)(gB + k0);
#pragma unroll
    for (int j = 0; j < 4; ++j) {
      float4 u0 = src[2 * j];
      float4 u1 = src[2 * j + 1];
      v8s pk;
      pk[0] = bfs(u0.x); pk[1] = bfs(u0.y); pk[2] = bfs(u0.z); pk[3] = bfs(u0.w);
      pk[4] = bfs(u1.x); pk[5] = bfs(u1.y); pk[6] = bfs(u1.z); pk[7] = bfs(u1.w);
      *(v8s*)&lsB[rB * 64 + cB + j * 8] = pk;
    }
    // A: async global->LDS (bf16, width 16)
#pragma unroll
    for (int i = 0; i < 4; ++i)
      gload_lds16(gA + (size_t)(i * 32) * K + k0, &lsA[i * 2048 + t * 8]);
    __syncthreads();
#pragma unroll
    for (int kk = 0; kk < 2; ++kk) {
      v8s af[4], bfr[4];
#pragma unroll
      for (int m = 0; m < 4; ++m)
        af[m] = *(const v8s*)&lsA[(wm * 64 + m * 16 + lr) * 64 + kk * 32 + lk * 8];
#pragma unroll
      for (int n = 0; n < 4; ++n)
        bfr[n] = *(const v8s*)&lsB[(wn * 64 + n * 16 + lr) * 64 + kk * 32 + lk * 8];
#pragma unroll
      for (int m = 0; m < 4; ++m)
#pragma unroll
        for (int n = 0; n < 4; ++n)
          acc[m][n] = __builtin_amdgcn_mfma_f32_16x16x32_bf16(af[m], bfr[n], acc[m][n], 0, 0, 0);
    }
    __syncthreads();
  }

#pragma unroll
  for (int n = 0; n < 4; ++n) {
    const int col = nBase + wn * 64 + n * 16 + lr;
    const float bv = bias[col];
#pragma unroll
    for (int m = 0; m < 4; ++m) {
      const int row0 = mBase + wm * 64 + m * 16 + lk * 4;
#pragma unroll
      for (int j = 0; j < 4; ++j) {
        float v = acc[m][n][j] + bv;
        v = v > 0.f ? v : 0.f;
        Cout[(size_t)(row0 + j) * N + col] = __float2bfloat16(v);
      }
    }
  }
}

// ---------------------------------------------------------------- layer2 + softmax + scatter
// X[128,64] = A[128rows,K]bf16 @ W2[64,K]f32^T + ltl[64]; softmax over learned
// cols; write out rows at global row = mGlob + local row.
__global__ __launch_bounds__(256) void gemm2_softmax_kernel(
    const bf16* __restrict__ Ain, const float* __restrict__ Bw,
    const float* __restrict__ ltl, const int* __restrict__ lidx,
    const int* __restrict__ aidx, int a, float* __restrict__ outp, int K,
    int mGlobBase) {
  __shared__ char smem[128 * 65 * 4];  // staging (24.5KB) then X (33.3KB)
  __shared__ int s_lidx[32];
  __shared__ int s_inv[64];
  __shared__ int s_arow;
  short* lsA = (short*)smem;
  short* lsB = (short*)(smem + 16384);
  float* X = (float*)smem;

  const int t = threadIdx.x;
  const int mBase = blockIdx.x * 128;
  const int w = t >> 6, lane = t & 63;
  const int lr = lane & 15, lk = lane >> 4;
  const int wm = w;

  if (t < 64) s_inv[t] = -1;
  __syncthreads();
  if (t < 32) {
    int q = lidx[t];
    s_lidx[t] = q;
    s_inv[q] = t;
  }
  if (t == 0) s_arow = aidx[a];
  __syncthreads();

  v4f acc[2][4];
#pragma unroll
  for (int m = 0; m < 2; ++m)
#pragma unroll
    for (int n = 0; n < 4; ++n) acc[m][n] = (v4f)(0.f);

  const int rowA = t >> 3;
  const int col8 = (t & 7) * 8;
  const bf16* gA = Ain + (size_t)(mBase + rowA) * K + col8;
  const int rB = t >> 2;            // 0..63
  const int cB = (t & 3) * 16;      // 0,16,32,48
  const float* gB = Bw + (size_t)rB * K + cB;

  for (int k0 = 0; k0 < K; k0 += 64) {
    const float4* src = (const float4*)(gB + k0);
#pragma unroll
    for (int j = 0; j < 2; ++j) {
      float4 u0 = src[2 * j];
      float4 u1 = src[2 * j + 1];
      v8s pk;
      pk[0] = bfs(u0.x); pk[1] = bfs(u0.y); pk[2] = bfs(u0.z); pk[3] = bfs(u0.w);
      pk[4] = bfs(u1.x); pk[5] = bfs(u1.y); pk[6] = bfs(u1.z); pk[7] = bfs(u1.w);
      *(v8s*)&lsB[rB * 64 + cB + j * 8] = pk;
    }
#pragma unroll
    for (int i = 0; i < 4; ++i)
      gload_lds16(gA + (size_t)(i * 32) * K + k0, &lsA[i * 2048 + t * 8]);
    __syncthreads();
#pragma unroll
    for (int kk = 0; kk < 2; ++kk) {
      v8s af[2], bfr[4];
#pragma unroll
      for (int m = 0; m < 2; ++m)
        af[m] = *(const v8s*)&lsA[(wm * 32 + m * 16 + lr) * 64 + kk * 32 + lk * 8];
#pragma unroll
      for (int n = 0; n < 4; ++n)
        bfr[n] = *(const v8s*)&lsB[(n * 16 + lr) * 64 + kk * 32 + lk * 8];
#pragma unroll
      for (int m = 0; m < 2; ++m)
#pragma unroll
        for (int n = 0; n < 4; ++n)
          acc[m][n] = __builtin_amdgcn_mfma_f32_16x16x32_bf16(af[m], bfr[n], acc[m][n], 0, 0, 0);
    }
    __syncthreads();
  }

  // logits into LDS X [128][65] (padded stride)
#pragma unroll
  for (int m = 0; m < 2; ++m) {
#pragma unroll
    for (int n = 0; n < 4; ++n) {
      const int col = n * 16 + lr;
      const float lc = ltl[col];
#pragma unroll
      for (int j = 0; j < 4; ++j) {
        const int row = wm * 32 + m * 16 + lk * 4 + j;
        X[row * 65 + col] = acc[m][n][j] + lc;
      }
    }
  }
  __syncthreads();

  if (t < 128) {
    const int r = t;
    float mx = -1e30f;
#pragma unroll
    for (int l = 0; l < 32; ++l) mx = fmaxf(mx, X[r * 65 + s_lidx[l]]);
    float s = 0.f;
#pragma unroll
    for (int l = 0; l < 32; ++l) s += __expf(X[r * 65 + s_lidx[l]] - mx);
    const float rs = 1.f / s;
    const size_t obase = ((size_t)(mGlobBase + mBase + r) * 64 + s_arow) * 64;
#pragma unroll
    for (int q0 = 0; q0 < 64; q0 += 4) {
      float4 v;
      v.x = (s_inv[q0 + 0] >= 0) ? __expf(X[r * 65 + q0 + 0] - mx) * rs : 0.f;
      v.y = (s_inv[q0 + 1] >= 0) ? __expf(X[r * 65 + q0 + 1] - mx) * rs : 0.f;
      v.z = (s_inv[q0 + 2] >= 0) ? __expf(X[r * 65 + q0 + 2] - mx) * rs : 0.f;
      v.w = (s_inv[q0 + 3] >= 0) ? __expf(X[r * 65 + q0 + 3] - mx) * rs : 0.f;
      *(float4*)&outp[obase + q0] = v;
    }
  }
}

// ---------------------------------------------------------------- launch
extern "C" void kernel_launch(void* const* d_in, const int* in_sizes, int n_in,
                              void* d_out, int out_size, void* d_ws, size_t ws_size,
                              hipStream_t stream) {
  const float* state = (const float*)d_in[0];
  const float* W0 = (const float*)d_in[1];
  const float* b0 = (const float*)d_in[2];
  const float* W1 = (const float*)d_in[3];
  const float* b1 = (const float*)d_in[4];
  const float* W2 = (const float*)d_in[5];
  const float* ltl = (const float*)d_in[6];
  const int* lidx = (const int*)d_in[7];
  const int* aidx = (const int*)d_in[8];
  float* outp = (float*)d_out;

  // Chunk the batch so ws usage = MC*5120 bytes (+512 slack) fits ws_size.
  int MC = Mtot;
  while (MC > 128 && (size_t)MC * 5120 + 512 > ws_size) MC >>= 1;

  char* ws = (char*)d_ws;
  bf16* stateb = (bf16*)ws;                              // MC*512*2
  bf16* h0 = (bf16*)(ws + (size_t)MC * Fdim * 2);        // MC*1024*2
  bf16* h1 = (bf16*)(ws + (size_t)MC * Fdim * 2 + (size_t)MC * Hdim * 2);

  ident_kernel<<<dim3(4096), dim3(256), 0, stream>>>(outp);

  for (int mOff = 0; mOff < Mtot; mOff += MC) {
    {
      int n4 = MC * Fdim / 4;
      int blocks = (n4 + 255) / 256;
      if (blocks > 2048) blocks = 2048;
      f32_to_bf16_kernel<<<dim3(blocks), dim3(256), 0, stream>>>(
          state + (size_t)mOff * Fdim, (unsigned short*)stateb, n4);
    }
    for (int a = 0; a < Aexp; ++a) {
      gemm_bias_relu_kernel<<<dim3(MC / 128, Hdim / 128), dim3(256), 0, stream>>>(
          stateb, W0 + (size_t)a * Hdim * Fdim, b0 + (size_t)a * Hdim, h0, Fdim, Hdim);
      gemm_bias_relu_kernel<<<dim3(MC / 128, Hdim / 128), dim3(256), 0, stream>>>(
          h0, W1 + (size_t)a * Hdim * Hdim, b1 + (size_t)a * Hdim, h1, Hdim, Hdim);
      gemm2_softmax_kernel<<<dim3(MC / 128), dim3(256), 0, stream>>>(
          h1, W2 + (size_t)a * Pdim * Hdim, ltl + (size_t)a * Pdim, lidx, aidx, a,
          outp, Hdim, mOff);
    }
  }
}

// Round 3
// 1040.151 us; speedup vs baseline: 1.6200x; 1.6200x over previous
//
#include <hip/hip_runtime.h>
#include <hip/hip_bf16.h>

// NEmbNet R3: pipelined 8-phase-style MFMA GEMMs (BM=128,BN=256,BK=64, 8 waves,
// triple-buffered LDS, counted vmcnt(6), XOR-swizzle via pre-swizzled global src),
// JIT piggyback f32->bf16 weight conversion (no extra launches), 256-block gemm2.
// ws usage ~43.2MB with chunking fallback (R1 lesson: ws_size < 90MB).

typedef short v8s __attribute__((ext_vector_type(8)));
typedef float v4f __attribute__((ext_vector_type(4)));
using bf16 = __hip_bfloat16;

#define AS_GLOBAL __attribute__((address_space(1)))
#define AS_LDS    __attribute__((address_space(3)))

static constexpr int Mtot = 8192;
static constexpr int Fdim = 512;
static constexpr int Hdim = 1024;
static constexpr int Pdim = 64;
static constexpr int Aexp = 16;

__device__ __forceinline__ void gload_lds16(const void* g, void* l) {
  __builtin_amdgcn_global_load_lds((const AS_GLOBAL void*)g, (AS_LDS void*)l, 16, 0, 0);
}
__device__ __forceinline__ unsigned short bfu(float x) {
  bf16 h = __float2bfloat16(x);
  return *(unsigned short*)&h;
}
#define MFMA16(d, a, b) d = __builtin_amdgcn_mfma_f32_16x16x32_bf16(a, b, d, 0, 0, 0)
#define WAIT_VM6 asm volatile("s_waitcnt vmcnt(6)" ::: "memory")
#define WAIT_VM3 asm volatile("s_waitcnt vmcnt(3)" ::: "memory")
#define WAIT_VM0 asm volatile("s_waitcnt vmcnt(0)" ::: "memory")
#define WAIT_LGKM0 asm volatile("s_waitcnt lgkmcnt(0)" ::: "memory")
#define BAR() __builtin_amdgcn_s_barrier()

__device__ __forceinline__ void cvt_span(const float* __restrict__ src,
                                         unsigned short* __restrict__ dst, int n4,
                                         int gid, int nthr) {
  for (int i = gid; i < n4; i += nthr) {
    float4 v = ((const float4*)src)[i];
    ushort4 u;
    u.x = bfu(v.x); u.y = bfu(v.y); u.z = bfu(v.z); u.w = bfu(v.w);
    ((ushort4*)dst)[i] = u;
  }
}

// ---------------------------------------------------------------- cvt kernel
__global__ void cvt2_kernel(const float* __restrict__ s1, unsigned short* __restrict__ d1,
                            int n41, const float* __restrict__ s2,
                            unsigned short* __restrict__ d2, int n42) {
  int gid = blockIdx.x * blockDim.x + threadIdx.x;
  int nthr = gridDim.x * blockDim.x;
  cvt_span(s1, d1, n41, gid, nthr);
  if (n42) cvt_span(s2, d2, n42, gid, nthr);
}

// ---------------------------------------------------------------- identity fill
__global__ void ident_kernel(float* __restrict__ outp) {
  const long total4 = (long)Mtot * Pdim * Pdim / 4;
  long i = blockIdx.x * 256 + threadIdx.x;
  const long stride = (long)gridDim.x * 256;
  for (; i < total4; i += stride) {
    long e = i * 4;
    int q = (int)(e & 63);
    int p = (int)((e >> 6) & 63);
    float4 v;
    v.x = (p == q) ? 1.f : 0.f;
    v.y = (p == q + 1) ? 1.f : 0.f;
    v.z = (p == q + 2) ? 1.f : 0.f;
    v.w = (p == q + 3) ? 1.f : 0.f;
    *(float4*)&outp[e] = v;
  }
}

// ---------------------------------------------------------------- pipelined GEMM
// C[M,1024] = relu(A[M,K]bf16 @ Bw[1024,K]bf16^T + bias); BM=128 BN=256 BK=64.
// 8 waves (wm 0..1, wn 0..3), per-wave 64x64 out = 4x4 16x16 frags.
// Triple-buffered LDS, 4 phases/K-tile, vmcnt(6) counted, XOR col-swizzle.
template <int NT>  // K = NT*64
__global__ __launch_bounds__(512, 2) void gemm8p_kernel(
    const bf16* __restrict__ Ain, const bf16* __restrict__ Bw,
    const float* __restrict__ bias, bf16* __restrict__ Cout,
    const float* __restrict__ cvA, unsigned short* __restrict__ cvAd, int cvAn4,
    const float* __restrict__ cvB, unsigned short* __restrict__ cvBd, int cvBn4) {
  constexpr int K = NT * 64;
  __shared__ short lsA[3][128 * 64];
  __shared__ short lsB[3][256 * 64];
  const int t = threadIdx.x;
  const int nbx = gridDim.x;
  const int nwg = gridDim.x * gridDim.y;
  const int flat = blockIdx.y * nbx + blockIdx.x;
  int swz = flat;
  if ((nwg & 7) == 0) {
    int q8 = nwg >> 3;
    swz = (flat & 7) * q8 + (flat >> 3);
  }
  const int mBase = (swz % nbx) * 128;
  const int nBase = (swz / nbx) * 256;
  const int w = t >> 6, lane = t & 63;
  const int wm = w >> 2, wn = w & 3;
  const int lr = lane & 15, lk = lane >> 4;

  // piggyback f32->bf16 conversion for downstream kernels
  {
    int gid = flat * 512 + t;
    int nthr = nwg * 512;
    if (cvAn4) cvt_span(cvA, cvAd, cvAn4, gid, nthr);
    if (cvBn4) cvt_span(cvB, cvBd, cvBn4, gid, nthr);
  }
  WAIT_VM0;  // drain cvt loads/stores so vmcnt counting below is exact

  // staging bases (pre-swizzled global source, linear LDS dest)
  const int srow = t >> 3;                              // 0..63 per round
  const int sg = (t & 7) ^ ((t >> 3) & 7);              // swizzled col granule
  const bf16* gA = Ain + (size_t)(mBase + srow) * K + sg * 8;
  const bf16* gB = Bw + (size_t)(nBase + srow) * K + sg * 8;

  auto stageA = [&](short* buf, int i, int kt2) {
    gload_lds16(gA + (size_t)(i * 64) * K + kt2 * 64, buf + i * 4096 + t * 8);
  };
  auto stageB = [&](short* buf, int i, int kt2) {
    gload_lds16(gB + (size_t)(i * 64) * K + kt2 * 64, buf + i * 4096 + t * 8);
  };

  v4f acc[4][4];
#pragma unroll
  for (int m = 0; m < 4; ++m)
#pragma unroll
    for (int n = 0; n < 4; ++n) acc[m][n] = (v4f)(0.f);

  // prologue: stage tiles 0 and 1
  stageA(lsA[0], 0, 0); stageA(lsA[0], 1, 0);
  stageB(lsB[0], 0, 0); stageB(lsB[0], 1, 0); stageB(lsB[0], 2, 0); stageB(lsB[0], 3, 0);
  stageA(lsA[1], 0, 1); stageA(lsA[1], 1, 1);
  stageB(lsB[1], 0, 1); stageB(lsB[1], 1, 1); stageB(lsB[1], 2, 1); stageB(lsB[1], 3, 1);
  WAIT_VM6;  // tile0 landed (tile1's 6 still in flight)
  BAR();

  int cb = 0, pb = 2;
  for (int kt = 0; kt < NT; ++kt) {
    const short* cA = lsA[cb];
    const short* cB = lsB[cb];
    short* pA = lsA[pb];
    short* pB = lsB[pb];
    const bool pf = (kt + 2) < NT;

    auto rdA = [&](int m, int s) -> v8s {
      int row = wm * 64 + m * 16 + lr;
      return *(const v8s*)&cA[row * 64 + ((((s << 2) + lk) ^ (row & 7)) << 3)];
    };
    auto rdB = [&](int n, int s) -> v8s {
      int row = wn * 64 + n * 16 + lr;
      return *(const v8s*)&cB[row * 64 + ((((s << 2) + lk) ^ (row & 7)) << 3)];
    };

    // ---- P1: s=0, n={0,1}; stage A of kt+2
    v8s a0 = rdA(0, 0), a1 = rdA(1, 0), a2 = rdA(2, 0), a3 = rdA(3, 0);
    v8s b0 = rdB(0, 0), b1 = rdB(1, 0);
    if (pf) { stageA(pA, 0, kt + 2); stageA(pA, 1, kt + 2); }
    BAR(); WAIT_LGKM0;
    __builtin_amdgcn_s_setprio(1);
    MFMA16(acc[0][0], a0, b0); MFMA16(acc[1][0], a1, b0);
    MFMA16(acc[2][0], a2, b0); MFMA16(acc[3][0], a3, b0);
    MFMA16(acc[0][1], a0, b1); MFMA16(acc[1][1], a1, b1);
    MFMA16(acc[2][1], a2, b1); MFMA16(acc[3][1], a3, b1);
    __builtin_amdgcn_s_setprio(0);
    BAR();

    // ---- P2: s=0, n={2,3}; stage B rounds 0,1 of kt+2
    v8s b2 = rdB(2, 0), b3 = rdB(3, 0);
    if (pf) { stageB(pB, 0, kt + 2); stageB(pB, 1, kt + 2); }
    BAR(); WAIT_LGKM0;
    __builtin_amdgcn_s_setprio(1);
    MFMA16(acc[0][2], a0, b2); MFMA16(acc[1][2], a1, b2);
    MFMA16(acc[2][2], a2, b2); MFMA16(acc[3][2], a3, b2);
    MFMA16(acc[0][3], a0, b3); MFMA16(acc[1][3], a1, b3);
    MFMA16(acc[2][3], a2, b3); MFMA16(acc[3][3], a3, b3);
    __builtin_amdgcn_s_setprio(0);
    BAR();

    // ---- P3: s=1, n={0,1}; stage B rounds 2,3 of kt+2
    a0 = rdA(0, 1); a1 = rdA(1, 1); a2 = rdA(2, 1); a3 = rdA(3, 1);
    b0 = rdB(0, 1); b1 = rdB(1, 1);
    if (pf) { stageB(pB, 2, kt + 2); stageB(pB, 3, kt + 2); }
    BAR(); WAIT_LGKM0;
    __builtin_amdgcn_s_setprio(1);
    MFMA16(acc[0][0], a0, b0); MFMA16(acc[1][0], a1, b0);
    MFMA16(acc[2][0], a2, b0); MFMA16(acc[3][0], a3, b0);
    MFMA16(acc[0][1], a0, b1); MFMA16(acc[1][1], a1, b1);
    MFMA16(acc[2][1], a2, b1); MFMA16(acc[3][1], a3, b1);
    __builtin_amdgcn_s_setprio(0);
    BAR();

    // ---- P4: s=1, n={2,3}; counted wait for tile kt+1
    b2 = rdB(2, 1); b3 = rdB(3, 1);
    if (kt + 2 < NT) { WAIT_VM6; } else { WAIT_VM0; }
    BAR(); WAIT_LGKM0;
    __builtin_amdgcn_s_setprio(1);
    MFMA16(acc[0][2], a0, b2); MFMA16(acc[1][2], a1, b2);
    MFMA16(acc[2][2], a2, b2); MFMA16(acc[3][2], a3, b2);
    MFMA16(acc[0][3], a0, b3); MFMA16(acc[1][3], a1, b3);
    MFMA16(acc[2][3], a2, b3); MFMA16(acc[3][3], a3, b3);
    __builtin_amdgcn_s_setprio(0);
    BAR();

    cb = (cb == 2) ? 0 : cb + 1;
    pb = (pb == 2) ? 0 : pb + 1;
  }

  // epilogue: bias + relu + bf16 store (validated C/D mapping: col=lane&15 ...)
#pragma unroll
  for (int n = 0; n < 4; ++n) {
    const int col = nBase + wn * 64 + n * 16 + lr;
    const float bv = bias[col];
#pragma unroll
    for (int m = 0; m < 4; ++m) {
      const int row0 = mBase + wm * 64 + m * 16 + lk * 4;
#pragma unroll
      for (int j = 0; j < 4; ++j) {
        float v = acc[m][n][j] + bv;
        v = v > 0.f ? v : 0.f;
        Cout[(size_t)(row0 + j) * Hdim + col] = __float2bfloat16(v);
      }
    }
  }
}

// ---------------------------------------------------------------- layer3 + softmax + scatter
// 32 rows/block, 256 blocks, 4 waves (wr=row-half, wq=col-half), K=1024.
__global__ __launch_bounds__(256) void gemm2_softmax_kernel(
    const bf16* __restrict__ Ain, const bf16* __restrict__ Bw,
    const float* __restrict__ ltl, const int* __restrict__ lidx,
    const int* __restrict__ aidx, int a, float* __restrict__ outp, int mGlobBase) {
  __shared__ short lsA[2][32 * 64];
  __shared__ short lsB[2][64 * 64];
  __shared__ float X[32][68];
  __shared__ int s_lidx[32];
  __shared__ int s_inv[64];
  __shared__ int s_arow;
  const int t = threadIdx.x;
  const int mBase = blockIdx.x * 32;
  const int w = t >> 6, lane = t & 63;
  const int lr = lane & 15, lk = lane >> 4;
  const int wr = w & 1, wq = w >> 1;

  if (t < 64) s_inv[t] = -1;
  __syncthreads();
  if (t < 32) {
    int q = lidx[t];
    s_lidx[t] = q;
    s_inv[q] = t;
  }
  if (t == 0) s_arow = aidx[a];
  __syncthreads();

  const int srow = t >> 3;
  const int sg = (t & 7) ^ ((t >> 3) & 7);
  const bf16* gA = Ain + (size_t)(mBase + srow) * Hdim + sg * 8;
  const bf16* gB = Bw + (size_t)srow * Hdim + sg * 8;

  auto stage = [&](int buf, int kt) {
    gload_lds16(gA + kt * 64, &lsA[buf][t * 8]);                       // 32 rows
    gload_lds16(gB + kt * 64, &lsB[buf][t * 8]);                       // rows 0..31
    gload_lds16(gB + (size_t)32 * Hdim + kt * 64, &lsB[buf][2048 + t * 8]);  // rows 32..63
  };

  v4f acc[2];
  acc[0] = (v4f)(0.f); acc[1] = (v4f)(0.f);

  stage(0, 0);
  for (int kt = 0; kt < 16; ++kt) {
    const int buf = kt & 1;
    if (kt + 1 < 16) { stage(buf ^ 1, kt + 1); WAIT_VM3; } else { WAIT_VM0; }
    BAR();
#pragma unroll
    for (int s = 0; s < 2; ++s) {
      int rowA = wr * 16 + lr;
      v8s af = *(const v8s*)&lsA[buf][rowA * 64 + ((((s << 2) + lk) ^ (rowA & 7)) << 3)];
#pragma unroll
      for (int n = 0; n < 2; ++n) {
        int rowB = wq * 32 + n * 16 + lr;
        v8s bf = *(const v8s*)&lsB[buf][rowB * 64 + ((((s << 2) + lk) ^ (rowB & 7)) << 3)];
        MFMA16(acc[n], af, bf);
      }
    }
    BAR();
  }

  // logits -> LDS
#pragma unroll
  for (int n = 0; n < 2; ++n) {
    const int col = wq * 32 + n * 16 + lr;
    const float lc = ltl[col];
#pragma unroll
    for (int j = 0; j < 4; ++j) {
      X[wr * 16 + lk * 4 + j][col] = acc[n][j] + lc;
    }
  }
  __syncthreads();

  if (t < 32) {
    const int r = t;
    float mx = -1e30f;
#pragma unroll
    for (int l = 0; l < 32; ++l) mx = fmaxf(mx, X[r][s_lidx[l]]);
    float s = 0.f;
#pragma unroll
    for (int l = 0; l < 32; ++l) s += __expf(X[r][s_lidx[l]] - mx);
    const float rs = 1.f / s;
    const size_t obase = ((size_t)(mGlobBase + mBase + r) * 64 + s_arow) * 64;
#pragma unroll
    for (int q0 = 0; q0 < 64; q0 += 4) {
      float4 v;
      v.x = (s_inv[q0 + 0] >= 0) ? __expf(X[r][q0 + 0] - mx) * rs : 0.f;
      v.y = (s_inv[q0 + 1] >= 0) ? __expf(X[r][q0 + 1] - mx) * rs : 0.f;
      v.z = (s_inv[q0 + 2] >= 0) ? __expf(X[r][q0 + 2] - mx) * rs : 0.f;
      v.w = (s_inv[q0 + 3] >= 0) ? __expf(X[r][q0 + 3] - mx) * rs : 0.f;
      *(float4*)&outp[obase + q0] = v;
    }
  }
}

// ---------------------------------------------------------------- launch
extern "C" void kernel_launch(void* const* d_in, const int* in_sizes, int n_in,
                              void* d_out, int out_size, void* d_ws, size_t ws_size,
                              hipStream_t stream) {
  const float* state = (const float*)d_in[0];
  const float* W0 = (const float*)d_in[1];
  const float* b0 = (const float*)d_in[2];
  const float* W1 = (const float*)d_in[3];
  const float* b1 = (const float*)d_in[4];
  const float* W2 = (const float*)d_in[5];
  const float* ltl = (const float*)d_in[6];
  const int* lidx = (const int*)d_in[7];
  const int* aidx = (const int*)d_in[8];
  float* outp = (float*)d_out;

  // ws budget: MC*5120 (stateb+h0+h1) + 3.125MB weight slots (+slack)
  const size_t wslots = (size_t)(Hdim * Fdim + Hdim * Hdim + Pdim * Hdim) * 2;
  int MC = Mtot;
  while (MC > 128 && (size_t)MC * 5120 + wslots + 4096 > ws_size) MC >>= 1;

  char* ws = (char*)d_ws;
  bf16* stateb = (bf16*)ws;
  bf16* h0 = (bf16*)(ws + (size_t)MC * 1024);
  bf16* h1 = (bf16*)(ws + (size_t)MC * 1024 + (size_t)MC * 2048);
  bf16* W0b = (bf16*)(ws + (size_t)MC * 5120);
  bf16* W1b = W0b + (size_t)Hdim * Fdim;
  bf16* W2b = W1b + (size_t)Hdim * Hdim;

  ident_kernel<<<dim3(4096), dim3(256), 0, stream>>>(outp);

  for (int mOff = 0; mOff < Mtot; mOff += MC) {
    // state chunk -> bf16, plus W0[0] -> bf16
    cvt2_kernel<<<dim3(1024), dim3(256), 0, stream>>>(
        state + (size_t)mOff * Fdim, (unsigned short*)stateb, MC * Fdim / 4,
        W0, (unsigned short*)W0b, Hdim * Fdim / 4);

    for (int a = 0; a < Aexp; ++a) {
      // L1: h0 = relu(state @ W0[a]^T + b0[a]); piggyback cvt W1[a], W2[a]
      gemm8p_kernel<Fdim / 64><<<dim3(MC / 128, 4), dim3(512), 0, stream>>>(
          stateb, W0b, b0 + (size_t)a * Hdim, h0,
          W1 + (size_t)a * Hdim * Hdim, (unsigned short*)W1b, Hdim * Hdim / 4,
          W2 + (size_t)a * Pdim * Hdim, (unsigned short*)W2b, Pdim * Hdim / 4);
      // L2: h1 = relu(h0 @ W1[a]^T + b1[a]); piggyback cvt W0[a+1]
      const bool more = (a + 1) < Aexp;
      gemm8p_kernel<Hdim / 64><<<dim3(MC / 128, 4), dim3(512), 0, stream>>>(
          h0, W1b, b1 + (size_t)a * Hdim, h1,
          more ? W0 + (size_t)(a + 1) * Hdim * Fdim : nullptr,
          (unsigned short*)W0b, more ? Hdim * Fdim / 4 : 0,
          nullptr, nullptr, 0);
      // L3 + softmax + scatter
      gemm2_softmax_kernel<<<dim3(MC / 32), dim3(256), 0, stream>>>(
          h1, W2b, ltl + (size_t)a * Pdim, lidx, aidx, a, outp, mOff);
    }
  }
}